// Round 10
// baseline (56.691 us; speedup 1.0000x reference)
//
#include <hip/hip_runtime.h>
#include <math.h>

// F0Resonance — bit-exact replication of XLA's tiled-scan cumsum (r6/r8/r9).
// jnp.cumsum lowers via ReduceWindowRewriter, base B=16: [32768]->[2048,16],
// sequential fp32 inner scans, recursive carry scan (2048->128->8), one fp32
// combine-add per level. phase(j) = fl(A0[j&15] + P1((j>>4)-1)),
// P1(m)=fl(B1[m&15]+P2(..)). contract(off) is REQUIRED: hipcc otherwise
// fuses mul+add -> f0ang off 1 ulp -> 0.03 rad at n=32768 (r7 failure).
// sin(exact fp32 phase): Cody-Waite (kq*C1 exact in fma: kq<=72e3, product
// < 2^24) + hw v_sin_f32 (REVOLUTIONS). Validated absmax = 1 bf16 quantum.
//
// r9->r10 perf: one block/row = 16 waves/CU capped occupancy (VALUBusy 51%).
// Split: K1 = 2048 blocks x 256 thr (one 16-sample scan window per thread,
// 32 waves/CU), raw osc stored in block-local PERMUTED layout (lane-contig
// stores), per-row max via commutative atomicMax. K2 = in-place block-local
// unpermute + scale (reads 4x256B runs, writes linear; barrier makes the
// in-place permute race-free via the vmcnt(0) drain before s_barrier).
#pragma clang fp contract(off)

constexpr int NSAMP = 32768;
constexpr int NROWS = 256;   // B*E = 4*64
constexpr int NOCT  = 16;
constexpr int SEGS  = 8;     // blocks per row (4096 samples each)
constexpr int TPB   = 256;
constexpr int GRID1 = NROWS * SEGS;   // 2048

// hard barrier against cross-statement fusion on the scalar chain
__device__ __forceinline__ float keepf(float x) {
  asm volatile("" : "+v"(x));
  return x;
}

__global__ __launch_bounds__(TPB, 8) void f0res_k1(
    const float* __restrict__ f0_in,
    const float* __restrict__ dec_in,
    const float* __restrict__ fs_in,
    float* __restrict__ out,
    unsigned int* __restrict__ rowmax)
{
  const int bid = blockIdx.x;
  const int row = bid >> 3;
  const int seg = bid & 7;
  const int t   = threadIdx.x;

  __shared__ float s_tab[NOCT][64];  // [0:16)=A0 [16:32)=B1 [32:48)=B2 [48:56)=B3
  __shared__ float s_w[NOCT];
  __shared__ float s_red[TPB / 64];

  // ---- fp32 scalar chain (reference roundings; contraction pinned off) ----
  const float f0a = fabsf(f0_in[row]);
  const float dcc = dec_in[row];
  const float fsv = fs_in[row];

  const float MIN_F = (float)(20.0 / 11025.0);
  const float RNG_F = (float)(3000.0 / 11025.0 - 20.0 / 11025.0);
  const float c1s   = keepf(f0a * RNG_F);       // fl32 mul
  const float c2s   = keepf(MIN_F + c1s);       // fl32 add (NOT fma)
  const float f0ang = keepf(c2s * (float)M_PI); // fl32 mul

  const float sg    = 1.0f / (1.0f + expf(-dcc));
  const float dvv   = 1.0f / (1.0f + expf(-sg));   // double sigmoid
  const float dvr   = keepf(dvv * 0.9405f);        // (1-0.01)*0.95
  const float decay = keepf(0.01f + dvr);          // fl32 add (NOT fma)
  const float ldv   = logf(decay + 1e-12f);

  // ---- builder: lane k builds octave k's tables + weight ----
  if (t < NOCT) {
    const int k = t;
    float fac = 0.0f;
    for (int j = 0; j <= k; ++j) fac = fac + fsv;   // 16-elem seq cumsum
    const float x = keepf(f0ang * fac);
    float* tab = s_tab[k];
    float a = 0.0f;
#pragma unroll
    for (int i = 0; i < 16; ++i) { a = a + x;  tab[i]      = a; }
    const float T0 = a; a = 0.0f;
#pragma unroll
    for (int i = 0; i < 16; ++i) { a = a + T0; tab[16 + i] = a; }
    const float T1 = a; a = 0.0f;
#pragma unroll
    for (int i = 0; i < 16; ++i) { a = a + T1; tab[32 + i] = a; }
    const float T2 = a; a = 0.0f;
#pragma unroll
    for (int i = 0; i < 8;  ++i) { a = a + T2; tab[48 + i] = a; }
    float lc = 0.0f;
    for (int j = 0; j <= k; ++j) lc = lc + ldv;     // seq cumsum of log_decay
    s_w[k] = expf(lc);
  }
  __syncthreads();

  // Cody-Waite: 2pi = C1 + C2. C1 = 201/32 (8-bit mantissa); kq <= ~72e3 so
  // kq*201 < 2^24 -> kq*C1 exact; residual arg err ~5e-6 rad.
  const float C1 = 6.28125f;
  const float C2 = (float)(6.283185307179586476925287 - 6.28125);
  const float INV2PI = (float)0.159154943091895335768883;

  // thread t owns scan window w = seg*256+t: samples j = 16w .. 16w+15
  const int m = seg * 256 + t - 1;   // level-0 carry window index

  float osc[16];
#pragma unroll
  for (int e = 0; e < 16; ++e) osc[e] = 0.0f;

  for (int k = 0; k < NOCT; ++k) {
    const float* tab = s_tab[k];
    // A0 into registers (4 x ds_read_b128, few distinct addrs -> broadcast)
    float tv[16];
    *(float4*)&tv[0]  = ((const float4*)tab)[0];
    *(float4*)&tv[4]  = ((const float4*)tab)[1];
    *(float4*)&tv[8]  = ((const float4*)tab)[2];
    *(float4*)&tv[12] = ((const float4*)tab)[3];
    const float w = s_w[k];

    // carry P1(m): exact fp32 per the tiled scan (pure adds)
    float carry = 0.0f;
    if (m >= 0) {
      carry = tab[16 + (m & 15)];
      const int m2 = (m >> 4) - 1;
      if (m2 >= 0) {
        float p2 = tab[32 + (m2 & 15)];
        const int m3 = (m2 >> 4) - 1;
        if (m3 >= 0) p2 = p2 + tab[48 + m3];
        carry = carry + p2;
      }
    }

#pragma unroll
    for (int e = 0; e < 16; ++e) {
      const float p = tv[e] + carry;                // exact ref phase bits
      const float kq = rintf(p * INV2PI);
      float r = __builtin_fmaf(-kq, C1, p);         // exact product in fma
      r = __builtin_fmaf(-kq, C2, r);
      const float fr = r * INV2PI;
      float sv;
      asm("v_sin_f32 %0, %1" : "=v"(sv) : "v"(fr)); // sin(fr * 2pi)
      // fma on the OUTPUT accumulation only (phase untouched): validated r9.
      osc[e] = __builtin_fmaf(w, sv, osc[e]);
    }
  }

  // ---- block |max| reduction -> one atomicMax per block ----
  float lmax = 0.0f;
#pragma unroll
  for (int e = 0; e < 16; ++e) lmax = fmaxf(lmax, fabsf(osc[e]));
#pragma unroll
  for (int off = 32; off >= 1; off >>= 1)
    lmax = fmaxf(lmax, __shfl_xor(lmax, off, 64));
  if ((t & 63) == 0) s_red[t >> 6] = lmax;
  __syncthreads();
  if (t == 0) {
    float mx = s_red[0];
#pragma unroll
    for (int i = 1; i < TPB / 64; ++i) mx = fmaxf(mx, s_red[i]);
    // osc values are finite, |.| >= 0: float-bit max == float max
    atomicMax(&rowmax[row], __float_as_uint(mx));
  }

  // ---- raw store, block-local PERMUTED layout (lane-contiguous) ----
  // raw f4 slot s = q*256 + t holds logical f4 (4t + q) of this 1024-f4 chunk
  float4* o4 = (float4*)out + (size_t)bid * 1024;
#pragma unroll
  for (int q = 0; q < 4; ++q) {
    float4 v;
    v.x = osc[4 * q + 0];
    v.y = osc[4 * q + 1];
    v.z = osc[4 * q + 2];
    v.w = osc[4 * q + 3];
    o4[q * 256 + t] = v;
  }
}

__global__ __launch_bounds__(TPB, 8) void f0res_k2(
    float* __restrict__ out,
    const unsigned int* __restrict__ rowmax)
{
  const int bid = blockIdx.x;
  const int t   = threadIdx.x;
  const int row = bid >> 3;

  const float mx  = __uint_as_float(rowmax[row]);
  const float inv = 1.0f / (mx + 1e-8f);

  float4* base = (float4*)out + (size_t)bid * 1024;

  // gather: logical f4 L = q*256+t lives at raw slot (t&3)*256 + 64q + (t>>2)
  float4 v[4];
#pragma unroll
  for (int q = 0; q < 4; ++q) {
    const int s = (t & 3) * 256 + 64 * q + (t >> 2);
    v[q] = base[s];
  }
  // __syncthreads emits s_waitcnt vmcnt(0) before s_barrier: all reads of
  // the chunk complete before any write below -> in-place permute is safe.
  __syncthreads();
#pragma unroll
  for (int q = 0; q < 4; ++q) {
    float4 x = v[q];
    x.x *= inv; x.y *= inv; x.z *= inv; x.w *= inv;
    base[q * 256 + t] = x;   // linear, lane-contiguous
  }
}

extern "C" void kernel_launch(void* const* d_in, const int* in_sizes, int n_in,
                              void* d_out, int out_size, void* d_ws, size_t ws_size,
                              hipStream_t stream) {
    const float* f0  = (const float*)d_in[0];  // (4,64,1)
    const float* dcc = (const float*)d_in[1];  // decay_coefficients
    // d_in[2] = phase_offsets: computed-but-unused in the reference
    const float* fsp = (const float*)d_in[3];  // freq_spacing
    float* out = (float*)d_out;                // (4,64,32768) fp32
    unsigned int* rowmax = (unsigned int*)d_ws;

    hipMemsetAsync(rowmax, 0, NROWS * sizeof(unsigned int), stream);
    f0res_k1<<<GRID1, TPB, 0, stream>>>(f0, dcc, fsp, out, rowmax);
    f0res_k2<<<GRID1, TPB, 0, stream>>>(out, rowmax);
}

// Round 12
// 50.103 us; speedup vs baseline: 1.1315x; 1.1315x over previous
//
#include <hip/hip_runtime.h>
#include <math.h>

// F0Resonance — bit-exact replication of XLA's tiled-scan cumsum (r6/r8/r9/r10).
// jnp.cumsum lowers via ReduceWindowRewriter, base B=16: [32768]->[2048,16],
// sequential fp32 inner scans, recursive carry scan (2048->128->8), one fp32
// combine-add per level. phase(j) = fl(A0[j&15] + P1((j>>4)-1)),
// P1(m)=fl(B1[m&15]+P2(..)). contract(off) REQUIRED (r7: hipcc fuses
// mul+add -> f0ang off 1 ulp -> 0.03 rad at n=32768). sin(exact fp32 phase):
// Cody-Waite (kq*C1 exact in fma: kq<=72e3) + hw v_sin_f32 (REVOLUTIONS).
// Validated absmax = 1 bf16 quantum.
//
// r11->r12: cooperative launch failed to execute (output zeros) -> back to
// two plain kernels. r10-K1's spill (VGPR 20, FETCH 58MB scratch) is fixed
// by r11's lean body (float4-at-a-time A0 reads, unroll 1 k-loop, osc[16]
// only). Cross-block max: plain per-segment stores into d_ws (all 2048
// slots written every call -> no memset, no atomics, poison-proof), K2
// maxes the row's 8 segments. K1 stores raw osc block-locally PERMUTED
// (lane-contiguous); K2 unpermutes in place (barrier makes it race-free),
// scales, writes linear. K2 block i reads K1 block i's chunk -> same
// dispatch slot -> same XCD -> L2-hot.
#pragma clang fp contract(off)

constexpr int NSAMP = 32768;
constexpr int NROWS = 256;   // B*E = 4*64
constexpr int NOCT  = 16;
constexpr int SEGS  = 8;     // blocks per row
constexpr int TPB   = 256;
constexpr int GRID  = NROWS * SEGS;   // 2048

// hard barrier against cross-statement fusion on the scalar chain
__device__ __forceinline__ float keepf(float x) {
  asm volatile("" : "+v"(x));
  return x;
}

__global__ __launch_bounds__(TPB, 8) void f0res_k1(
    const float* __restrict__ f0_in,
    const float* __restrict__ dec_in,
    const float* __restrict__ fs_in,
    float* __restrict__ out,
    float* __restrict__ segmax)
{
  const int bid = blockIdx.x;
  const int row = bid >> 3;
  const int seg = bid & 7;
  const int t   = threadIdx.x;

  __shared__ float s_tab[NOCT][64];  // [0:16)=A0 [16:32)=B1 [32:48)=B2 [48:56)=B3
  __shared__ float s_w[NOCT];
  __shared__ float s_red[TPB / 64];

  // ---- fp32 scalar chain (reference roundings; contraction pinned off) ----
  const float f0a = fabsf(f0_in[row]);
  const float dcc = dec_in[row];
  const float fsv = fs_in[row];

  const float MIN_F = (float)(20.0 / 11025.0);
  const float RNG_F = (float)(3000.0 / 11025.0 - 20.0 / 11025.0);
  const float c1s   = keepf(f0a * RNG_F);       // fl32 mul
  const float c2s   = keepf(MIN_F + c1s);       // fl32 add (NOT fma)
  const float f0ang = keepf(c2s * (float)M_PI); // fl32 mul

  const float sg    = 1.0f / (1.0f + expf(-dcc));
  const float dvv   = 1.0f / (1.0f + expf(-sg));   // double sigmoid
  const float dvr   = keepf(dvv * 0.9405f);        // (1-0.01)*0.95
  const float decay = keepf(0.01f + dvr);          // fl32 add (NOT fma)
  const float ldv   = logf(decay + 1e-12f);

  // ---- builder: lane k builds octave k's tables + weight ----
  if (t < NOCT) {
    const int k = t;
    float fac = 0.0f;
    for (int j = 0; j <= k; ++j) fac = fac + fsv;   // 16-elem seq cumsum
    const float x = keepf(f0ang * fac);
    float* tab = s_tab[k];
    float a = 0.0f;
#pragma unroll
    for (int i = 0; i < 16; ++i) { a = a + x;  tab[i]      = a; }
    const float T0 = a; a = 0.0f;
#pragma unroll
    for (int i = 0; i < 16; ++i) { a = a + T0; tab[16 + i] = a; }
    const float T1 = a; a = 0.0f;
#pragma unroll
    for (int i = 0; i < 16; ++i) { a = a + T1; tab[32 + i] = a; }
    const float T2 = a; a = 0.0f;
#pragma unroll
    for (int i = 0; i < 8;  ++i) { a = a + T2; tab[48 + i] = a; }
    float lc = 0.0f;
    for (int j = 0; j <= k; ++j) lc = lc + ldv;     // seq cumsum of log_decay
    s_w[k] = expf(lc);
  }
  __syncthreads();

  // Cody-Waite: 2pi = C1 + C2. C1 = 6.28125 (8-bit mantissa); kq <= ~72e3 so
  // kq*C1 exact inside fma; residual arg err ~5e-6 rad.
  const float C1 = 6.28125f;
  const float C2 = (float)(6.283185307179586476925287 - 6.28125);
  const float INV2PI = (float)0.159154943091895335768883;

  // thread t owns scan window w = seg*256+t: samples j = 16w .. 16w+15
  const int m = seg * 256 + t - 1;   // level-0 carry window index

  float osc[16];
#pragma unroll
  for (int e = 0; e < 16; ++e) osc[e] = 0.0f;

#pragma unroll 1   // keep register pressure under the 64-VGPR cap
  for (int k = 0; k < NOCT; ++k) {
    const float* tab = s_tab[k];
    const float4* tab4 = (const float4*)tab;
    const float w = s_w[k];

    // carry P1(m): exact fp32 per the tiled scan (pure adds)
    float carry = 0.0f;
    if (m >= 0) {
      carry = tab[16 + (m & 15)];
      const int m2 = (m >> 4) - 1;
      if (m2 >= 0) {
        float p2 = tab[32 + (m2 & 15)];
        const int m3 = (m2 >> 4) - 1;
        if (m3 >= 0) p2 = p2 + tab[48 + m3];
        carry = carry + p2;
      }
    }

#pragma unroll
    for (int g = 0; g < 4; ++g) {
      const float4 tv4 = tab4[g];   // A0[4g..4g+3], uniform addr -> broadcast
#pragma unroll
      for (int c = 0; c < 4; ++c) {
        const int e = 4 * g + c;
        const float a0 = (c == 0) ? tv4.x : (c == 1) ? tv4.y
                        : (c == 2) ? tv4.z : tv4.w;
        const float p = a0 + carry;                   // exact ref phase bits
        const float kq = rintf(p * INV2PI);
        float r = __builtin_fmaf(-kq, C1, p);         // exact product in fma
        r = __builtin_fmaf(-kq, C2, r);
        const float fr = r * INV2PI;
        float sv;
        asm("v_sin_f32 %0, %1" : "=v"(sv) : "v"(fr)); // sin(fr * 2pi)
        // fma on OUTPUT accumulation only (phase untouched): validated r9.
        osc[e] = __builtin_fmaf(w, sv, osc[e]);
      }
    }
  }

  // ---- block |max| reduction -> plain store (no init, no atomic) ----
  float lmax = 0.0f;
#pragma unroll
  for (int e = 0; e < 16; ++e) lmax = fmaxf(lmax, fabsf(osc[e]));
#pragma unroll
  for (int off = 32; off >= 1; off >>= 1)
    lmax = fmaxf(lmax, __shfl_xor(lmax, off, 64));
  if ((t & 63) == 0) s_red[t >> 6] = lmax;
  __syncthreads();
  if (t == 0) {
    float mx = s_red[0];
#pragma unroll
    for (int i = 1; i < TPB / 64; ++i) mx = fmaxf(mx, s_red[i]);
    segmax[bid] = mx;
  }

  // ---- raw store, block-local PERMUTED layout (lane-contiguous) ----
  // raw f4 slot s = q*256 + t holds logical f4 (4t + q) of this 1024-f4 chunk
  float4* o4 = (float4*)out + (size_t)bid * 1024;
#pragma unroll
  for (int q = 0; q < 4; ++q) {
    float4 v;
    v.x = osc[4 * q + 0];
    v.y = osc[4 * q + 1];
    v.z = osc[4 * q + 2];
    v.w = osc[4 * q + 3];
    o4[q * 256 + t] = v;
  }
}

__global__ __launch_bounds__(TPB, 8) void f0res_k2(
    float* __restrict__ out,
    const float* __restrict__ segmax)
{
  const int bid = blockIdx.x;
  const int t   = threadIdx.x;
  const int row = bid >> 3;

  float mx = 0.0f;
#pragma unroll
  for (int i = 0; i < SEGS; ++i) mx = fmaxf(mx, segmax[row * SEGS + i]);
  const float inv = 1.0f / (mx + 1e-8f);

  float4* base = (float4*)out + (size_t)bid * 1024;

  // gather: logical f4 L = q*256+t lives at raw slot (t&3)*256 + 64q + (t>>2)
  float4 v[4];
#pragma unroll
  for (int q = 0; q < 4; ++q) {
    const int s = (t & 3) * 256 + 64 * q + (t >> 2);
    v[q] = base[s];
  }
  // __syncthreads emits s_waitcnt vmcnt(0) before s_barrier: all reads of
  // the chunk complete before any write below -> in-place permute is safe.
  __syncthreads();
#pragma unroll
  for (int q = 0; q < 4; ++q) {
    float4 x = v[q];
    x.x *= inv; x.y *= inv; x.z *= inv; x.w *= inv;
    base[q * 256 + t] = x;   // linear, lane-contiguous
  }
}

extern "C" void kernel_launch(void* const* d_in, const int* in_sizes, int n_in,
                              void* d_out, int out_size, void* d_ws, size_t ws_size,
                              hipStream_t stream) {
    const float* f0  = (const float*)d_in[0];  // (4,64,1)
    const float* dcc = (const float*)d_in[1];  // decay_coefficients
    // d_in[2] = phase_offsets: computed-but-unused in the reference
    const float* fsp = (const float*)d_in[3];  // freq_spacing
    float* out = (float*)d_out;                // (4,64,32768) fp32
    float* segmax = (float*)d_ws;              // 2048 floats, fully written/call

    f0res_k1<<<GRID, TPB, 0, stream>>>(f0, dcc, fsp, out, segmax);
    f0res_k2<<<GRID, TPB, 0, stream>>>(out, segmax);
}